// Round 2
// baseline (521.252 us; speedup 1.0000x reference)
//
#include <hip/hip_runtime.h>
#include <stdint.h>

// Problem dims
#define BDIM 8
#define CDIM 32
#define NDIM 512
#define TDIM 168
#define KG   2048          // GEMM K = 4 slices * 512 nodes
#define NJ   43008         // 256 (b,o) * 168 l
#define ALPHA_ 0.05f
#define BETA_  0.95f

typedef __attribute__((ext_vector_type(8))) short short8;
typedef __attribute__((ext_vector_type(4))) float f32x4;

__device__ __forceinline__ unsigned short f2bf(float f) {
  union { float f; unsigned int u; } v; v.f = f;
  unsigned int r = v.u + 0x7fffu + ((v.u >> 16) & 1u);
  return (unsigned short)(r >> 16);
}
__device__ __forceinline__ float bf2f(unsigned short h) {
  union { unsigned int u; float f; } v; v.u = ((unsigned int)h) << 16;
  return v.f;
}
__device__ __forceinline__ void gload_lds16(const void* g, void* l) {
  __builtin_amdgcn_global_load_lds((const __attribute__((address_space(1))) void*)g,
                                   (__attribute__((address_space(3))) void*)l, 16, 0, 0);
}

// ---- prep: row sums of (adp + I) and (adp^T + I) ----
__global__ void gc_prep(const float* __restrict__ adp, float* __restrict__ rs) {
  int v = blockIdx.x, t = threadIdx.x;
  float sA = 0.f, sB = 0.f;
  for (int w = t; w < NDIM; w += 256) { sA += adp[v * NDIM + w]; sB += adp[w * NDIM + v]; }
  __shared__ float red[2][256];
  red[0][t] = sA; red[1][t] = sB; __syncthreads();
  for (int s = 128; s > 0; s >>= 1) {
    if (t < s) { red[0][t] += red[0][t + s]; red[1][t] += red[1][t + s]; }
    __syncthreads();
  }
  if (t == 0) { rs[v] = 1.f + red[0][0]; rs[NDIM + v] = 1.f + red[1][0]; }
}

// ---- build A (slice 0) and A' (slice 2) into chunked G2[(k>>3)][n][8], plus fp32 copies ----
__global__ void gc_build(const float* __restrict__ adp, const float* __restrict__ rs,
                         float* __restrict__ Af, unsigned short* __restrict__ G2) {
  int v = blockIdx.x, t = threadIdx.x;
  float ra = 1.f / rs[v], rb = 1.f / rs[NDIM + v];
  for (int w = t; w < NDIM; w += 256) {
    float d = (v == w) ? 1.f : 0.f;
    float a  = (adp[v * NDIM + w] + d) * ra;   // A[v][w]
    float a2 = (adp[w * NDIM + v] + d) * rb;   // A'[v][w]
    Af[(size_t)v * NDIM + w] = a;
    Af[(size_t)NDIM * NDIM + (size_t)v * NDIM + w] = a2;
    // k = s*512 + w ; chunk = (s*64 + (w>>3))*512 + v ; elem = w&7
    G2[(size_t)(((0 * 64) + (w >> 3)) * 512 + v) * 8 + (w & 7)] = f2bf(a);
    G2[(size_t)(((2 * 64) + (w >> 3)) * 512 + v) * 8 + (w & 7)] = f2bf(a2);
  }
}

// ---- A^2 (slice 1) and A'^2 (slice 3) into G2 ----
__global__ void gc_sq(const float* __restrict__ Af, unsigned short* __restrict__ G2) {
  int mat = blockIdx.x >> 6, tile = blockIdx.x & 63;
  int v0 = (tile >> 3) * 64, w0 = (tile & 7) * 64;
  const float* M = Af + (size_t)mat * NDIM * NDIM;
  __shared__ float T1[64][64];
  __shared__ float T2[64][65];
  int t = threadIdx.x;
  float acc[4][4] = {};
  for (int u0 = 0; u0 < NDIM; u0 += 64) {
    for (int idx = t; idx < 64 * 64; idx += 256) {
      int r = idx >> 6, c2 = idx & 63;
      T1[r][c2] = M[(size_t)(v0 + r) * NDIM + u0 + c2];
      T2[r][c2] = M[(size_t)(u0 + r) * NDIM + w0 + c2];
    }
    __syncthreads();
    int ty = t >> 4, tx = t & 15;
    for (int u = 0; u < 64; ++u) {
      float b0 = T2[u][tx * 4], b1v = T2[u][tx * 4 + 1], b2v = T2[u][tx * 4 + 2], b3v = T2[u][tx * 4 + 3];
      #pragma unroll
      for (int i = 0; i < 4; ++i) {
        float a = T1[ty * 4 + i][u];
        acc[i][0] += a * b0; acc[i][1] += a * b1v; acc[i][2] += a * b2v; acc[i][3] += a * b3v;
      }
    }
    __syncthreads();
  }
  int ty = t >> 4, tx = t & 15;
  int sl = mat ? 3 : 1;
  for (int i = 0; i < 4; ++i)
    for (int j = 0; j < 4; ++j) {
      int v = v0 + ty * 4 + i, w = w0 + tx * 4 + j;
      G2[(size_t)((sl * 64 + (w >> 3)) * 512 + v) * 8 + (w & 7)] = f2bf(acc[i][j]);
    }
}

// ---- folded channel-mix matrices, bf16: Ub[160][32] rows = {U1,U2,V1,V2,U0'}; bias = b1+b2 ----
__global__ void gc_ucat(const float* __restrict__ W1, const float* __restrict__ b1,
                        const float* __restrict__ W2, const float* __restrict__ b2,
                        unsigned short* __restrict__ Ub, float* __restrict__ bias) {
  int t = threadIdx.x;
  for (int idx = t; idx < 160 * 32; idx += 256) {
    int ko = idx >> 5, c = idx & 31, o = ko & 31, s = ko >> 5;
    float v;
    if (s == 0)      v = BETA_ * (W1[o * 96 + 32 + c] + ALPHA_ * W1[o * 96 + 64 + c]);
    else if (s == 1) v = BETA_ * BETA_ * W1[o * 96 + 64 + c];
    else if (s == 2) v = BETA_ * (W2[o * 96 + 32 + c] + ALPHA_ * W2[o * 96 + 64 + c]);
    else if (s == 3) v = BETA_ * BETA_ * W2[o * 96 + 64 + c];
    else             v = W1[o * 96 + c] + ALPHA_ * (W1[o * 96 + 32 + c] + W1[o * 96 + 64 + c])
                       + W2[o * 96 + c] + ALPHA_ * (W2[o * 96 + 32 + c] + W2[o * 96 + 64 + c]);
    Ub[idx] = f2bf(v);
  }
  if (t < 32) bias[t] = b1[t] + b2[t];
}

// ---- channel-mix via MFMA: P[kbg][j][8] bf16 and R0[bo][n][l] bf16 ----
// grid 2688 = 8 b * 336 position-tiles of 256; 256 threads (4 waves, 4 col-groups each)
__global__ __launch_bounds__(256, 4) void gc_mix2(const float* __restrict__ x,
    const unsigned short* __restrict__ Ub, unsigned short* __restrict__ Pg,
    unsigned short* __restrict__ R0) {
  __shared__ __align__(16) float Xs[32 * 256];   // [c 32][pos 256] f32, 32KB
  int bid = blockIdx.x;
  int b = bid / 336, tile = bid - b * 336;
  int pos0 = tile * 256;
  int tid = threadIdx.x, wid = tid >> 6, lane = tid & 63;

  // stage x[b][:][pos0:pos0+256] -> LDS (fully coalesced, 8 x 16B per thread)
  #pragma unroll
  for (int q = 0; q < 8; ++q) {
    int f = q * 256 + tid;               // 16B chunk id, 2048 total
    int c = f >> 6, pc = f & 63;
    const float* src = x + (size_t)(b * 32 + c) * 86016 + pos0 + pc * 4;
    gload_lds16(src, Xs + f * 4);
  }
  __syncthreads();   // drains vmcnt(0)

  // A-fragments from Ub (row = lane&15, k-chunk = (lane>>4)*8)
  short8 uF[10];
  #pragma unroll
  for (int mt = 0; mt < 10; ++mt)
    uF[mt] = *(const short8*)(Ub + (size_t)(mt * 16 + (lane & 15)) * 32 + (lane >> 4) * 8);

  int hi4 = (lane >> 4) * 4;
  #pragma unroll
  for (int cc = 0; cc < 4; ++cc) {
    int cg = wid * 4 + cc;
    int pos = pos0 + cg * 16 + (lane & 15);
    int w = pos / 168;
    int l = pos - w * 168;
    // B-fragment: 8 c-values for this position
    short8 bfrag;
    #pragma unroll
    for (int i = 0; i < 8; ++i) {
      float xv = Xs[((lane >> 4) * 8 + i) * 256 + cg * 16 + (lane & 15)];
      bfrag[i] = (short)f2bf(xv);
    }
    size_t baseW = ((size_t)(w >> 3) * NJ + (size_t)(b * 32) * 168 + l) * 8 + (w & 7);
    size_t baseR = ((size_t)(b * 32) * 512 + w) * 168 + l;
    #pragma unroll
    for (int mt = 0; mt < 10; ++mt) {
      f32x4 zero = {0.f, 0.f, 0.f, 0.f};
      f32x4 p = __builtin_amdgcn_mfma_f32_16x16x32_bf16(uF[mt], bfrag, zero, 0, 0, 0);
      int ob = ((mt & 1) << 4) + hi4;          // o base for this lane-group
      if (mt < 8) {
        int s = mt >> 1;
        #pragma unroll
        for (int r = 0; r < 4; ++r)
          Pg[baseW + (size_t)s * 22020096 + (size_t)(ob + r) * 1344] = f2bf(p[r]);
      } else {
        #pragma unroll
        for (int r = 0; r < 4; ++r)
          R0[baseR + (size_t)(ob + r) * 86016] = f2bf(p[r]);
      }
    }
  }
}

// ---- main GEMM: C[512 n][43008 j] = G[512][2048] * P[2048][43008], + R0 + bias ----
// 672 blocks (2 nt * 336 jt), 256 threads = 4 waves (2M x 2N), per-wave 128x64 out
// BM=256 BN=128 BK=32, double-buffered LDS 48KB, counted vmcnt(6), setprio.
__global__ __launch_bounds__(256, 2) void gc_gemm2(const unsigned short* __restrict__ G2,
    const unsigned short* __restrict__ Pg, const unsigned short* __restrict__ R0,
    const float* __restrict__ bias, float* __restrict__ out) {
  int bid = blockIdx.x;
  int swz = (bid & 7) * 84 + (bid >> 3);       // XCD-chunked bijective swizzle (672 = 8*84)
  int nt = swz & 1, jt = swz >> 1;             // nt fastest: the 2 blocks sharing a B-panel co-run
  int n0 = nt * 256, j0 = jt * 128;

  __shared__ __align__(16) unsigned short Ab[2][8192];  // [kb 4][n 256][8]
  __shared__ __align__(16) unsigned short Bb[2][4096];  // [kb 4][j 128][8]
  int tid = threadIdx.x, lane = tid & 63, wid = tid >> 6;
  int wm = wid >> 1, wn = wid & 1;

  // staging offsets (chunk units of 8 shorts / 16B)
  int offA[4], offB[2], dA[4], dB[2];
  #pragma unroll
  for (int q = 0; q < 4; ++q) {
    int f = q * 256 + tid;
    offA[q] = (f >> 8) * 512 + n0 + (f & 255);
    dA[q] = f * 8;
  }
  #pragma unroll
  for (int q = 0; q < 2; ++q) {
    int f = q * 256 + tid;
    offB[q] = (f >> 7) * NJ + j0 + (f & 127);
    dB[q] = f * 8;
  }

  auto stage = [&](int buf, int kt) {
    // kt-th K-tile of 32: global kbg base = kt*4
    #pragma unroll
    for (int q = 0; q < 4; ++q)
      gload_lds16(G2 + ((size_t)kt * 2048 + offA[q]) * 8, &Ab[buf][dA[q]]);
    #pragma unroll
    for (int q = 0; q < 2; ++q)
      gload_lds16(Pg + ((size_t)kt * 4 * NJ + offB[q]) * 8, &Bb[buf][dB[q]]);
  };

  f32x4 acc[8][4] = {};

  stage(0, 0);
  stage(1, 1);
  asm volatile("s_waitcnt vmcnt(6)" ::: "memory");
  __builtin_amdgcn_s_barrier();

  int aoff = (lane >> 4) * 2048 + (wm * 128 + (lane & 15)) * 8;
  int boff = (lane >> 4) * 1024 + (wn * 64 + (lane & 15)) * 8;

  for (int t = 0; t < 64; ++t) {
    const int cur = t & 1;
    short8 aF[8], bF[4];
    #pragma unroll
    for (int fi = 0; fi < 8; ++fi) aF[fi] = *(const short8*)&Ab[cur][aoff + fi * 128];
    #pragma unroll
    for (int fj = 0; fj < 4; ++fj) bF[fj] = *(const short8*)&Bb[cur][boff + fj * 128];
    asm volatile("s_waitcnt lgkmcnt(0)" ::: "memory");
    __builtin_amdgcn_sched_barrier(0);
    __builtin_amdgcn_s_barrier();            // all waves done reading buf[cur]
    if (t < 62) stage(cur, t + 2);           // overwrite buf[cur] with tile t+2 (6 loads in flight)
    __builtin_amdgcn_s_setprio(1);
    #pragma unroll
    for (int fi = 0; fi < 8; ++fi)
      #pragma unroll
      for (int fj = 0; fj < 4; ++fj)
        acc[fi][fj] = __builtin_amdgcn_mfma_f32_16x16x32_bf16(aF[fi], bF[fj], acc[fi][fj], 0, 0, 0);
    __builtin_amdgcn_s_setprio(0);
    if (t < 62) { asm volatile("s_waitcnt vmcnt(6)" ::: "memory"); }
    else        { asm volatile("s_waitcnt vmcnt(0)" ::: "memory"); }
    __builtin_amdgcn_sched_barrier(0);
    __builtin_amdgcn_s_barrier();            // tile t+1 (buf[cur^1]) visible to all
  }

  // epilogue: out[(bo*512+n)*168+l] = acc + R0 + bias[o]
  #pragma unroll
  for (int fj = 0; fj < 4; ++fj) {
    int jj = j0 + wn * 64 + fj * 16 + (lane & 15);
    int bo = jj / 168;
    int l = jj - bo * 168;
    float bs = bias[bo & 31];
    size_t obase = (size_t)bo * 86016 + l;
    #pragma unroll
    for (int fi = 0; fi < 8; ++fi) {
      #pragma unroll
      for (int r = 0; r < 4; ++r) {
        int n = n0 + wm * 128 + fi * 16 + (lane >> 4) * 4 + r;
        size_t idx = obase + (size_t)n * 168;
        out[idx] = acc[fi][fj][r] + bf2f(R0[idx]) + bs;
      }
    }
  }
}

extern "C" void kernel_launch(void* const* d_in, const int* in_sizes, int n_in,
                              void* d_out, int out_size, void* d_ws, size_t ws_size,
                              hipStream_t stream) {
  const float* x   = (const float*)d_in[0];
  const float* adp = (const float*)d_in[1];
  const float* W1  = (const float*)d_in[2];
  const float* b1  = (const float*)d_in[3];
  const float* W2  = (const float*)d_in[4];
  const float* b2  = (const float*)d_in[5];
  float* out = (float*)d_out;

  char* w = (char*)d_ws;
  unsigned short* Pg  = (unsigned short*)(w);                  // 176,160,768 B
  unsigned short* R0  = (unsigned short*)(w + 176160768ULL);   //  44,040,192 B
  unsigned short* G2  = (unsigned short*)(w + 220200960ULL);   //   2,097,152 B
  float* Af           = (float*)(w + 222298112ULL);            //   2,097,152 B
  float* rs           = (float*)(w + 224395264ULL);            //       4,096 B
  unsigned short* Ub  = (unsigned short*)(w + 224399360ULL);   //      16,384 B (10,240 used)
  float* bias         = (float*)(w + 224415744ULL);            //         128 B
  if (ws_size < 224415872ULL) return;                          // need ~214 MiB

  gc_prep<<<512, 256, 0, stream>>>(adp, rs);
  gc_build<<<512, 256, 0, stream>>>(adp, rs, Af, G2);
  gc_sq<<<128, 256, 0, stream>>>(Af, G2);
  gc_ucat<<<1, 256, 0, stream>>>(W1, b1, W2, b2, Ub, bias);
  gc_mix2<<<2688, 256, 0, stream>>>(x, Ub, Pg, R0);
  gc_gemm2<<<672, 256, 0, stream>>>(G2, Pg, R0, bias, out);
}

// Round 3
// 331.648 us; speedup vs baseline: 1.5717x; 1.5717x over previous
//
#include <hip/hip_runtime.h>
#include <stdint.h>

// Problem dims
#define BDIM 8
#define CDIM 32
#define NDIM 512
#define TDIM 168
#define KG   2048          // GEMM K = 4 slices * 512 nodes
#define NJ   43008         // 256 (b,o) * 168 l
#define ALPHA_ 0.05f
#define BETA_  0.95f

typedef __attribute__((ext_vector_type(8))) short short8;
typedef __attribute__((ext_vector_type(4))) float f32x4;
typedef __attribute__((ext_vector_type(4))) float f4v;
typedef __attribute__((ext_vector_type(4))) unsigned short u16x4;

__device__ __forceinline__ unsigned short f2bf(float f) {
  union { float f; unsigned int u; } v; v.f = f;
  unsigned int r = v.u + 0x7fffu + ((v.u >> 16) & 1u);
  return (unsigned short)(r >> 16);
}
__device__ __forceinline__ float bf2f(unsigned short h) {
  union { unsigned int u; float f; } v; v.u = ((unsigned int)h) << 16;
  return v.f;
}
__device__ __forceinline__ void gload_lds16(const void* g, void* l) {
  __builtin_amdgcn_global_load_lds((const __attribute__((address_space(1))) void*)g,
                                   (__attribute__((address_space(3))) void*)l, 16, 0, 0);
}

// ---- prep: row sums of (adp + I) and (adp^T + I) ----
__global__ void gc_prep(const float* __restrict__ adp, float* __restrict__ rs) {
  int v = blockIdx.x, t = threadIdx.x;
  float sA = 0.f, sB = 0.f;
  for (int w = t; w < NDIM; w += 256) { sA += adp[v * NDIM + w]; sB += adp[w * NDIM + v]; }
  __shared__ float red[2][256];
  red[0][t] = sA; red[1][t] = sB; __syncthreads();
  for (int s = 128; s > 0; s >>= 1) {
    if (t < s) { red[0][t] += red[0][t + s]; red[1][t] += red[1][t + s]; }
    __syncthreads();
  }
  if (t == 0) { rs[v] = 1.f + red[0][0]; rs[NDIM + v] = 1.f + red[1][0]; }
}

// ---- build A (slice 0) and A' (slice 2) into chunked G2[(k>>3)][n][8], plus fp32 copies ----
__global__ void gc_build(const float* __restrict__ adp, const float* __restrict__ rs,
                         float* __restrict__ Af, unsigned short* __restrict__ G2) {
  int v = blockIdx.x, t = threadIdx.x;
  float ra = 1.f / rs[v], rb = 1.f / rs[NDIM + v];
  for (int w = t; w < NDIM; w += 256) {
    float d = (v == w) ? 1.f : 0.f;
    float a  = (adp[v * NDIM + w] + d) * ra;   // A[v][w]
    float a2 = (adp[w * NDIM + v] + d) * rb;   // A'[v][w]
    Af[(size_t)v * NDIM + w] = a;
    Af[(size_t)NDIM * NDIM + (size_t)v * NDIM + w] = a2;
    G2[(size_t)(((0 * 64) + (w >> 3)) * 512 + v) * 8 + (w & 7)] = f2bf(a);
    G2[(size_t)(((2 * 64) + (w >> 3)) * 512 + v) * 8 + (w & 7)] = f2bf(a2);
  }
}

// ---- A^2 (slice 1) and A'^2 (slice 3) into G2 ----
__global__ void gc_sq(const float* __restrict__ Af, unsigned short* __restrict__ G2) {
  int mat = blockIdx.x >> 6, tile = blockIdx.x & 63;
  int v0 = (tile >> 3) * 64, w0 = (tile & 7) * 64;
  const float* M = Af + (size_t)mat * NDIM * NDIM;
  __shared__ float T1[64][64];
  __shared__ float T2[64][65];
  int t = threadIdx.x;
  float acc[4][4] = {};
  for (int u0 = 0; u0 < NDIM; u0 += 64) {
    for (int idx = t; idx < 64 * 64; idx += 256) {
      int r = idx >> 6, c2 = idx & 63;
      T1[r][c2] = M[(size_t)(v0 + r) * NDIM + u0 + c2];
      T2[r][c2] = M[(size_t)(u0 + r) * NDIM + w0 + c2];
    }
    __syncthreads();
    int ty = t >> 4, tx = t & 15;
    for (int u = 0; u < 64; ++u) {
      float b0 = T2[u][tx * 4], b1v = T2[u][tx * 4 + 1], b2v = T2[u][tx * 4 + 2], b3v = T2[u][tx * 4 + 3];
      #pragma unroll
      for (int i = 0; i < 4; ++i) {
        float a = T1[ty * 4 + i][u];
        acc[i][0] += a * b0; acc[i][1] += a * b1v; acc[i][2] += a * b2v; acc[i][3] += a * b3v;
      }
    }
    __syncthreads();
  }
  int ty = t >> 4, tx = t & 15;
  int sl = mat ? 3 : 1;
  for (int i = 0; i < 4; ++i)
    for (int j = 0; j < 4; ++j) {
      int v = v0 + ty * 4 + i, w = w0 + tx * 4 + j;
      G2[(size_t)((sl * 64 + (w >> 3)) * 512 + v) * 8 + (w & 7)] = f2bf(acc[i][j]);
    }
}

// ---- folded channel-mix matrices, bf16: Ub[160][32] rows = {U1,U2,V1,V2,U0'}; bias = b1+b2 ----
__global__ void gc_ucat(const float* __restrict__ W1, const float* __restrict__ b1,
                        const float* __restrict__ W2, const float* __restrict__ b2,
                        unsigned short* __restrict__ Ub, float* __restrict__ bias) {
  int t = threadIdx.x;
  for (int idx = t; idx < 160 * 32; idx += 256) {
    int ko = idx >> 5, c = idx & 31, o = ko & 31, s = ko >> 5;
    float v;
    if (s == 0)      v = BETA_ * (W1[o * 96 + 32 + c] + ALPHA_ * W1[o * 96 + 64 + c]);
    else if (s == 1) v = BETA_ * BETA_ * W1[o * 96 + 64 + c];
    else if (s == 2) v = BETA_ * (W2[o * 96 + 32 + c] + ALPHA_ * W2[o * 96 + 64 + c]);
    else if (s == 3) v = BETA_ * BETA_ * W2[o * 96 + 64 + c];
    else             v = W1[o * 96 + c] + ALPHA_ * (W1[o * 96 + 32 + c] + W1[o * 96 + 64 + c])
                       + W2[o * 96 + c] + ALPHA_ * (W2[o * 96 + 32 + c] + W2[o * 96 + 64 + c]);
    Ub[idx] = f2bf(v);
  }
  if (t < 32) bias[t] = b1[t] + b2[t];
}

// ---- channel-mix via MFMA + LDS transpose: all global writes are 16B chunks ----
// grid 1024 = 8 b * 64 wtiles(8 nodes) * 2 l-halves(80/88); 512 threads (8 waves)
__global__ __launch_bounds__(512, 4) void gc_mix3(const float* __restrict__ x,
    const unsigned short* __restrict__ Ub, unsigned short* __restrict__ Pg,
    unsigned short* __restrict__ R0) {
  __shared__ __align__(16) unsigned short Xs[32 * 704];  // [c][pos = w*L + ll] bf16
  __shared__ __align__(16) unsigned short Tb[16 * 712];  // [o16][pos] transpose buffer
  int bid = blockIdx.x;
  int h = bid & 1, wt = (bid >> 1) & 63, b = bid >> 7;
  int L = h ? 88 : 80, l0 = h * 80, w0 = wt * 8;
  int NF4 = L >> 2;            // float4 per row: 20 / 22
  int NT = L >> 1;             // 16-pos col tiles: 40 / 44
  int tid = threadIdx.x, wv = tid >> 6, lane = tid & 63;
  int l15 = lane & 15, hi = lane >> 4;

  // stage x[b][:][w0..w0+7][l0..l0+L) -> Xs bf16 (float4 reads, exact count)
  int iters = NF4 >> 1;        // 10 / 11
  for (int q = 0; q < iters; ++q) {
    int idx = q * 512 + tid;
    int row = idx / NF4, c4 = idx - row * NF4;
    int c = row >> 3, w = row & 7;
    f4v v = *(const f4v*)(x + (size_t)((b * 32 + c) * 512 + w0 + w) * 168 + l0 + c4 * 4);
    u16x4 pk = { f2bf(v[0]), f2bf(v[1]), f2bf(v[2]), f2bf(v[3]) };
    *(u16x4*)&Xs[c * 704 + w * L + c4 * 4] = pk;
  }
  __syncthreads();

  // U fragments (A-operand) -- verified layout from round 2
  short8 uF[10];
  #pragma unroll
  for (int mt = 0; mt < 10; ++mt)
    uF[mt] = *(const short8*)(Ub + (size_t)(mt * 16 + l15) * 32 + hi * 8);

  // x fragments (B-operand), one per assigned col-tile, reused across all 10 mt
  short8 bfr[6];
  #pragma unroll
  for (int i = 0; i < 6; ++i) {
    int ct = wv + 8 * i;
    if (ct < NT) {
      int pos = ct * 16 + l15;
      #pragma unroll
      for (int j = 0; j < 8; ++j)
        bfr[i][j] = (short)Xs[(hi * 8 + j) * 704 + pos];
    }
  }

  int o4 = hi * 4;
  for (int mt = 0; mt < 10; ++mt) {
    // compute this 16-o group, scatter into LDS transpose buffer
    #pragma unroll
    for (int i = 0; i < 6; ++i) {
      int ct = wv + 8 * i;
      if (ct < NT) {
        f32x4 z = {0.f, 0.f, 0.f, 0.f};
        f32x4 p = __builtin_amdgcn_mfma_f32_16x16x32_bf16(uF[mt], bfr[i], z, 0, 0, 0);
        int pos = ct * 16 + l15;
        #pragma unroll
        for (int r = 0; r < 4; ++r)
          Tb[(o4 + r) * 712 + pos] = f2bf(p[r]);
      }
    }
    __syncthreads();
    // coalesced 16B read-out
    if (mt < 8) {
      int s = mt >> 1, ohi = (mt & 1) << 4;
      size_t kbg = (size_t)(s * 64 + wt);
      int total = 16 * L;
      #pragma unroll
      for (int k = 0; k < 3; ++k) {
        int chunk = tid + 512 * k;
        if (chunk < total) {
          int o16 = chunk / L, ll = chunk - o16 * L;
          short8 vv;
          #pragma unroll
          for (int w = 0; w < 8; ++w)
            vv[w] = (short)Tb[o16 * 712 + w * L + ll];
          *(short8*)(Pg + (kbg * NJ + (size_t)(b * 32 + ohi + o16) * 168 + l0 + ll) * 8) = vv;
        }
      }
    } else {
      int ohi = (mt & 1) << 4;
      int lgc = L >> 3;                   // 10 / 11
      int total = 128 * lgc;
      #pragma unroll
      for (int k = 0; k < 3; ++k) {
        int chunk = tid + 512 * k;
        if (chunk < total) {
          int o16 = chunk / (lgc * 8);
          int rem = chunk - o16 * lgc * 8;
          int w = rem / lgc, lg = rem - w * lgc;
          short8 vv = *(const short8*)&Tb[o16 * 712 + w * L + lg * 8];
          *(short8*)(R0 + ((size_t)(b * 32 + ohi + o16) * 512 + w0 + w) * 168 + l0 + lg * 8) = vv;
        }
      }
    }
    __syncthreads();
  }
}

// ---- main GEMM: C[512 n][43008 j] = G[512][2048] * P[2048][43008], + R0 + bias ----
// 672 blocks (2 nt * 336 jt), 512 threads = 8 waves (4M x 2N), wave tile 64x64
// BM=256 BN=128 BK=64, double-buffered 96KB LDS, counted vmcnt(6), setprio.
__global__ __launch_bounds__(512, 2) void gc_gemm3(const unsigned short* __restrict__ G2,
    const unsigned short* __restrict__ Pg, const unsigned short* __restrict__ R0,
    const float* __restrict__ bias, float* __restrict__ out) {
  int bid = blockIdx.x;
  int swz = (bid & 7) * 84 + (bid >> 3);   // XCD-chunked bijective swizzle (672 = 8*84)
  int nt = swz & 1, jt = swz >> 1;         // nt fastest: B-panel pair adjacent on same XCD
  int n0 = nt * 256, j0 = jt * 128;

  __shared__ __align__(16) unsigned short Ab[2][16384];  // [kb 8][n 256][8]
  __shared__ __align__(16) unsigned short Bb[2][8192];   // [kb 8][j 128][8]
  int tid = threadIdx.x, lane = tid & 63, wid = tid >> 6;
  int wm = wid >> 1, wn = wid & 1;
  int l15 = lane & 15, hi = lane >> 4;

  auto stage = [&](int buf, int kt) {
    #pragma unroll
    for (int q = 0; q < 4; ++q) {
      int f = q * 512 + tid;
      int kb = f >> 8, row = f & 255;
      gload_lds16(G2 + ((size_t)((kt * 8 + kb) * 512) + n0 + row) * 8, &Ab[buf][f * 8]);
    }
    #pragma unroll
    for (int q = 0; q < 2; ++q) {
      int g = q * 512 + tid;
      int kb = g >> 7, row = g & 127;
      gload_lds16(Pg + ((size_t)(kt * 8 + kb) * NJ + j0 + row) * 8, &Bb[buf][g * 8]);
    }
  };

  f32x4 acc[4][4] = {};
  stage(0, 0);
  stage(1, 1);

  int aoffs = (wm * 64 + l15) * 8;   // + mi*128 + (kc*4+hi)*2048
  int boffs = (wn * 64 + l15) * 8;   // + nj*128 + (kc*4+hi)*1024

  for (int t = 0; t < 32; ++t) {
    const int cur = t & 1;
    if (t < 30) asm volatile("s_waitcnt vmcnt(6)" ::: "memory");
    else        asm volatile("s_waitcnt vmcnt(0)" ::: "memory");
    __builtin_amdgcn_s_barrier();              // tile t (buf cur) fully staged

    short8 aF[2][4], bF[2][4];
    #pragma unroll
    for (int kc = 0; kc < 2; ++kc) {
      #pragma unroll
      for (int mi = 0; mi < 4; ++mi)
        aF[kc][mi] = *(const short8*)&Ab[cur][(kc * 4 + hi) * 2048 + aoffs + mi * 128];
      #pragma unroll
      for (int nj = 0; nj < 4; ++nj)
        bF[kc][nj] = *(const short8*)&Bb[cur][(kc * 4 + hi) * 1024 + boffs + nj * 128];
    }
    asm volatile("s_waitcnt lgkmcnt(0)" ::: "memory");
    __builtin_amdgcn_sched_barrier(0);
    __builtin_amdgcn_s_barrier();              // all waves done reading buf cur

    if (t < 30) stage(cur, t + 2);             // overwrite cur with tile t+2 (6 loads in flight)

    __builtin_amdgcn_s_setprio(1);
    #pragma unroll
    for (int kc = 0; kc < 2; ++kc)
      #pragma unroll
      for (int mi = 0; mi < 4; ++mi)
        #pragma unroll
        for (int nj = 0; nj < 4; ++nj)
          acc[mi][nj] = __builtin_amdgcn_mfma_f32_16x16x32_bf16(aF[kc][mi], bF[kc][nj], acc[mi][nj], 0, 0, 0);
    __builtin_amdgcn_s_setprio(0);
  }

  // epilogue: out[(bo*512+n)*168+l] = acc + R0 + bias[o]
  #pragma unroll
  for (int fj = 0; fj < 4; ++fj) {
    int jj = j0 + wn * 64 + fj * 16 + l15;
    int bo = jj / 168;
    int l = jj - bo * 168;
    float bs = bias[bo & 31];
    size_t obase = (size_t)bo * 86016 + l;
    #pragma unroll
    for (int mi = 0; mi < 4; ++mi) {
      #pragma unroll
      for (int r = 0; r < 4; ++r) {
        int n = n0 + wm * 64 + mi * 16 + hi * 4 + r;
        size_t idx = obase + (size_t)n * 168;
        out[idx] = acc[mi][fj][r] + bf2f(R0[idx]) + bs;
      }
    }
  }
}

extern "C" void kernel_launch(void* const* d_in, const int* in_sizes, int n_in,
                              void* d_out, int out_size, void* d_ws, size_t ws_size,
                              hipStream_t stream) {
  const float* x   = (const float*)d_in[0];
  const float* adp = (const float*)d_in[1];
  const float* W1  = (const float*)d_in[2];
  const float* b1  = (const float*)d_in[3];
  const float* W2  = (const float*)d_in[4];
  const float* b2  = (const float*)d_in[5];
  float* out = (float*)d_out;

  char* w = (char*)d_ws;
  unsigned short* Pg  = (unsigned short*)(w);                  // 176,160,768 B
  unsigned short* R0  = (unsigned short*)(w + 176160768ULL);   //  44,040,192 B
  unsigned short* G2  = (unsigned short*)(w + 220200960ULL);   //   2,097,152 B
  float* Af           = (float*)(w + 222298112ULL);            //   2,097,152 B
  float* rs           = (float*)(w + 224395264ULL);            //       4,096 B
  unsigned short* Ub  = (unsigned short*)(w + 224399360ULL);   //      16,384 B (10,240 used)
  float* bias         = (float*)(w + 224415744ULL);            //         128 B
  if (ws_size < 224415872ULL) return;                          // need ~214 MiB

  gc_prep<<<512, 256, 0, stream>>>(adp, rs);
  gc_build<<<512, 256, 0, stream>>>(adp, rs, Af, G2);
  gc_sq<<<128, 256, 0, stream>>>(Af, G2);
  gc_ucat<<<1, 256, 0, stream>>>(W1, b1, W2, b2, Ub, bias);
  gc_mix3<<<1024, 512, 0, stream>>>(x, Ub, Pg, R0);
  gc_gemm3<<<672, 512, 0, stream>>>(G2, Pg, R0, bias, out);
}